// Round 9
// baseline (143.694 us; speedup 1.0000x reference)
//
#include <hip/hip_runtime.h>
#include <math.h>

#define BB 8
#define TT 2048
#define DD 1024
#define HSZ 64

typedef __bf16 bf16_t;
typedef bf16_t bf16x8 __attribute__((ext_vector_type(8)));
typedef bf16_t bf16x4 __attribute__((ext_vector_type(4)));
typedef float f32x4 __attribute__((ext_vector_type(4)));

#define MFMA16(A, B, C) __builtin_amdgcn_mfma_f32_16x16x32_bf16(A, B, C, 0, 0, 0)

// MFMA 16x16x32 bf16 fragment conventions:
//   A-frag: lane = quad*16+l16 holds A[m=l16][k=quad*8+j]
//   B-frag: lane = quad*16+l16 holds B[k=quad*8+j][n=l16]
//   C/D   : lane holds D[m=quad*4+reg][n=l16]
// Frag-ordered buffers store one 32k x 16n B-tile as [lane][8] -> one
// coalesced 16B/lane read.  K/V frag base for (b,kt) = ((b*32+kt)*8)*512.

// ---------------------------------------------------------------------------
__global__ __launch_bounds__(256) void wt_convert(
    const float* __restrict__ Wq, const float* __restrict__ Wk,
    const float* __restrict__ Wv, bf16_t* __restrict__ Wtf)
{
    int id = blockIdx.x * 256 + threadIdx.x;      // 0 .. 196607
    int j = id & 7;
    int lane = (id >> 3) & 63;
    int chunk = (id >> 9) & 31;
    int nt = id >> 14;
    int l16 = lane & 15, quad = lane >> 4;
    int k = chunk * 32 + quad * 8 + j;
    int col = nt * 16 + l16;
    int m = col >> 6, ncol = col & 63;
    const float* W = (m == 0) ? Wq : (m == 1) ? Wk : Wv;
    float scl = (m == 0) ? 0.18033688f : 1.0f;    // 0.125 * log2(e)
    Wtf[id] = (bf16_t)(W[k * HSZ + ncol] * scl);
}

// ---------------------------------------------------------------------------
// QKV projection, in-block k-split.  1024 blocks x 4 waves; wave w covers
// k in [w*256, w*256+256) for the block's 16 rows.  Flat 12-load B batch
// per chunk (compiler batches + one waitcnt).  Cross-wave reduction in 3
// staggered rounds over a 16 KB buffer -> 4 blocks/CU resident (4 waves/
// SIMD) to hide the ~200-300cyc L2 latency the registers won't.
// Round r: all waves write acc[4r..4r+3]; wave w reduces tile nt=4r+w;
// r=0 stores Q, r=1 Kf (g=w), r=2 Vf (dt=w).  All acc[] indices compile-
// time (no scratch); runtime w only appears in LDS/global addressing.
// ---------------------------------------------------------------------------
__global__ __launch_bounds__(256, 3) void qkv_proj(
    const float* __restrict__ ctx, const bf16_t* __restrict__ Wtf,
    bf16_t* __restrict__ Q, bf16_t* __restrict__ Kf, bf16_t* __restrict__ Vf)
{
    __shared__ f32x4 red[4][4][64];   // 16 KB

    const int tid = threadIdx.x;
    const int w = tid >> 6, lane = tid & 63;
    const int quad = lane >> 4, l16 = lane & 15;
    const size_t row0 = (size_t)blockIdx.x * 16;
    const int k0 = w * 256;

    f32x4 acc[12];
    #pragma unroll
    for (int i = 0; i < 12; ++i) acc[i] = (f32x4){0.f, 0.f, 0.f, 0.f};

    const float* arow = ctx + (row0 + l16) * DD + k0 + quad * 8;
    const bf16_t* wbase = Wtf + lane * 8;

    #pragma unroll
    for (int kc = 0; kc < 256; kc += 32) {
        const int chunk = (k0 + kc) >> 5;
        bf16x8 bfr[12];
        #pragma unroll
        for (int nt = 0; nt < 12; ++nt)
            bfr[nt] = *(const bf16x8*)(wbase + ((size_t)nt * 32 + chunk) * 512);
        float4 a0 = *(const float4*)(arow + kc);
        float4 a1 = *(const float4*)(arow + kc + 4);
        bf16x8 af;
        af[0] = (bf16_t)a0.x; af[1] = (bf16_t)a0.y;
        af[2] = (bf16_t)a0.z; af[3] = (bf16_t)a0.w;
        af[4] = (bf16_t)a1.x; af[5] = (bf16_t)a1.y;
        af[6] = (bf16_t)a1.z; af[7] = (bf16_t)a1.w;
        #pragma unroll
        for (int nt = 0; nt < 12; ++nt)
            acc[nt] = MFMA16(af, bfr[nt], acc[nt]);
    }

    const int bb   = (int)(row0 >> 11);
    const int tloc = (int)(row0 & 2047);
    const int kt   = tloc >> 6;
    const int nn   = (tloc >> 4) & 3;

    #pragma unroll
    for (int r = 0; r < 3; ++r) {
        if (r) __syncthreads();                 // buffer reuse
        #pragma unroll
        for (int i = 0; i < 4; ++i) red[w][i][lane] = acc[r * 4 + i];
        __syncthreads();

        f32x4 s = red[0][w][lane];
        s += red[1][w][lane];
        s += red[2][w][lane];
        s += red[3][w][lane];

        if (r == 0) {          // Q col-tile w, row-major
            const int col = w * 16 + l16;
            #pragma unroll
            for (int reg = 0; reg < 4; ++reg)
                Q[(row0 + quad * 4 + reg) * HSZ + col] = (bf16_t)s[reg];
        } else if (r == 1) {   // K -> frag order (kt, n=nn, ks); g = w
            const int ks = w >> 1;
            const int quadf = (w & 1) * 2 + (l16 >> 3);
            const int jj = l16 & 7;
            const size_t fb = ((((size_t)bb * 32 + kt) * 4 + nn) * 2 + ks) * 512;
            #pragma unroll
            for (int reg = 0; reg < 4; ++reg)
                Kf[fb + (quadf * 16 + quad * 4 + reg) * 8 + jj] = (bf16_t)s[reg];
        } else {               // V -> frag order (kt, ks, dt=w)
            const int t0 = tloc + quad * 4;
            const int ks = (t0 >> 5) & 1;
            const int quadf = (t0 >> 3) & 3;
            const int j0 = t0 & 7;
            const size_t fb = ((((size_t)bb * 32 + kt) * 2 + ks) * 4 + w) * 512;
            bf16x4 v;
            #pragma unroll
            for (int reg = 0; reg < 4; ++reg) v[reg] = (bf16_t)s[reg];
            *(bf16x4*)(Vf + fb + (quadf * 16 + l16) * 8 + j0) = v;
        }
    }
}

// ---------------------------------------------------------------------------
// Split-K=4 flash attention; K frags double-buffered across k-tiles.
// All K/V fragment loads unconditional (tile rows always < T); causal
// correctness comes from the P zero-fill, not from skipping loads.
// ---------------------------------------------------------------------------
__device__ __forceinline__ void load_kfrags(
    const bf16_t* __restrict__ Kf, size_t bofs, int kt, int lane, bf16x8* kf)
{
    const bf16_t* kbase = Kf + ((bofs + (size_t)kt) * 8) * 512 + lane * 8;
    #pragma unroll
    for (int i = 0; i < 8; ++i)
        kf[i] = *(const bf16x8*)(kbase + i * 512);
}

__global__ __launch_bounds__(64, 3) void attn_kernel(
    const bf16_t* __restrict__ Q, const bf16_t* __restrict__ Kf,
    const bf16_t* __restrict__ Vf,
    float* __restrict__ Opart, float* __restrict__ Lpart)
{
    __shared__ bf16_t Ps[16][76];

    const int lane = threadIdx.x;
    const int quad = lane >> 4, l16 = lane & 15;

    const int z = blockIdx.x;
    const int b = z & 7, c = z >> 3;
    const int j = 127 - (c >> 2);
    const int seg = c & 3;
    const size_t base = (size_t)b * TT * HSZ;
    const size_t bofs = (size_t)b * 32;           // tile units
    const int ntile = (j >> 2) + 1, jm = j & 3;

    const bf16_t* qp = Q + base + (size_t)(j * 16 + l16) * HSZ + quad * 8;
    bf16x8 qf0 = *(const bf16x8*)qp;
    bf16x8 qf1 = *(const bf16x8*)(qp + 32);

    bf16x8 onesf;
    {
        bf16_t e = (l16 == 0) ? (bf16_t)1.0f : (bf16_t)0.0f;
        #pragma unroll
        for (int i = 0; i < 8; ++i) onesf[i] = e;
    }

    f32x4 o[4];
    #pragma unroll
    for (int dt = 0; dt < 4; ++dt) o[dt] = (f32x4){0.f, 0.f, 0.f, 0.f};
    f32x4 lacc = (f32x4){0.f, 0.f, 0.f, 0.f};

    bf16x8 kA[8], kB[8];

    auto process = [&](int kt, const bf16x8* kf) {
        const bool last = (kt == ntile - 1);
        const int nv = last ? jm + 1 : 4;
        const int ksm = (nv > 2) ? 2 : 1;

        const bf16_t* vbase = Vf + ((bofs + (size_t)kt) * 8) * 512 + lane * 8;
        bf16x8 vf[8];
        #pragma unroll
        for (int i = 0; i < 8; ++i)
            vf[i] = *(const bf16x8*)(vbase + i * 512);   // [dt] then [4+dt]

        f32x4 sc[4];
        #pragma unroll
        for (int n = 0; n < 4; ++n) {
            if (n < nv) {
                f32x4 a = (f32x4){0.f, 0.f, 0.f, 0.f};
                a = MFMA16(qf0, kf[2 * n], a);
                a = MFMA16(qf1, kf[2 * n + 1], a);
                sc[n] = a;
            }
        }

        if (last) {
            #pragma unroll
            for (int n = 0; n < 4; ++n) {
                if (n < nv) {
                    #pragma unroll
                    for (int reg = 0; reg < 4; ++reg) {
                        bool masked = (n == jm) && (l16 > quad * 4 + reg);
                        float p = __builtin_amdgcn_exp2f(sc[n][reg]);
                        sc[n][reg] = masked ? 0.f : p;
                    }
                }
            }
        } else {
            #pragma unroll
            for (int n = 0; n < 4; ++n)
                #pragma unroll
                for (int reg = 0; reg < 4; ++reg)
                    sc[n][reg] = __builtin_amdgcn_exp2f(sc[n][reg]);
        }

        #pragma unroll
        for (int n = 0; n < 4; ++n) {
            #pragma unroll
            for (int reg = 0; reg < 4; ++reg) {
                float p = (n < nv) ? sc[n][reg] : 0.f;
                Ps[quad * 4 + reg][n * 16 + l16] = (bf16_t)p;
            }
        }
        bf16x8 pf0 = *(const bf16x8*)&Ps[l16][quad * 8];
        bf16x8 pf1 = *(const bf16x8*)&Ps[l16][32 + quad * 8];

        #pragma unroll
        for (int dt = 0; dt < 4; ++dt) {
            o[dt] = MFMA16(pf0, vf[dt], o[dt]);
            if (ksm == 2) o[dt] = MFMA16(pf1, vf[4 + dt], o[dt]);
        }
        lacc = MFMA16(pf0, onesf, lacc);
        if (ksm == 2) lacc = MFMA16(pf1, onesf, lacc);
    };

    // software-pipelined pair loop: load(t+4) before process(t)
    if (seg < ntile) {
        load_kfrags(Kf, bofs, seg, lane, kA);
        for (int kt = seg; kt < ntile; kt += 8) {
            if (kt + 4 < ntile) load_kfrags(Kf, bofs, kt + 4, lane, kB);
            process(kt, kA);
            if (kt + 4 < ntile) {
                if (kt + 8 < ntile) load_kfrags(Kf, bofs, kt + 8, lane, kA);
                process(kt + 4, kB);
            }
        }
    }

    float* op = Opart + (size_t)z * 16 * 64;
    #pragma unroll
    for (int dt = 0; dt < 4; ++dt) {
        #pragma unroll
        for (int reg = 0; reg < 4; ++reg)
            op[(quad * 4 + reg) * 64 + dt * 16 + l16] = o[dt][reg];
    }
    if (l16 == 0) {
        #pragma unroll
        for (int reg = 0; reg < 4; ++reg)
            Lpart[z * 16 + quad * 4 + reg] = lacc[reg];
    }
}

// ---------------------------------------------------------------------------
__global__ __launch_bounds__(256) void combine_kernel(
    const float* __restrict__ Opart, const float* __restrict__ Lpart,
    float* __restrict__ O)
{
    int gid = blockIdx.x * 256 + threadIdx.x;   // 0 .. 1048575
    int col = gid & 63;
    int row = (gid >> 6) & 15;
    int j   = (gid >> 10) & 127;
    int b   = gid >> 17;
    int z0 = ((127 - j) * 4) * 8 + b;
    float l = 0.f, ov = 0.f;
    #pragma unroll
    for (int s = 0; s < 4; ++s) {
        l  += Lpart[(z0 + 8 * s) * 16 + row];
        ov += Opart[((size_t)(z0 + 8 * s) * 16 + row) * 64 + col];
    }
    O[((size_t)b * TT + j * 16 + row) * 64 + col] = ov / l;
}

// ---------------------------------------------------------------------------
extern "C" void kernel_launch(void* const* d_in, const int* in_sizes, int n_in,
                              void* d_out, int out_size, void* d_ws, size_t ws_size,
                              hipStream_t stream) {
    const float* ctx = (const float*)d_in[0];
    const float* Wq  = (const float*)d_in[1];
    const float* Wk  = (const float*)d_in[2];
    const float* Wv  = (const float*)d_in[3];
    float* out = (float*)d_out;

    const size_t NQ = (size_t)BB * TT * HSZ;       // 1,048,576
    bf16_t* Qw  = (bf16_t*)d_ws;
    bf16_t* Kfw = Qw + NQ;                         // frag-ordered
    bf16_t* Vfw = Kfw + NQ;                        // frag-ordered
    bf16_t* Wtf = Vfw + NQ;                        // frag-ordered
    float*  Opart = (float*)(Wtf + 196608);        // [4096][16][64]
    float*  Lpart = Opart + (size_t)4096 * 1024;   // [4096][16]

    wt_convert<<<768, 256, 0, stream>>>(Wq, Wk, Wv, Wtf);
    qkv_proj<<<1024, 256, 0, stream>>>(ctx, Wtf, Qw, Kfw, Vfw);
    attn_kernel<<<4096, 64, 0, stream>>>(Qw, Kfw, Vfw, Opart, Lpart);
    combine_kernel<<<4096, 256, 0, stream>>>(Opart, Lpart, out);
}

// Round 10
// 128.521 us; speedup vs baseline: 1.1181x; 1.1181x over previous
//
#include <hip/hip_runtime.h>
#include <math.h>

#define BB 8
#define TT 2048
#define DD 1024
#define HSZ 64

typedef __bf16 bf16_t;
typedef bf16_t bf16x8 __attribute__((ext_vector_type(8)));
typedef bf16_t bf16x4 __attribute__((ext_vector_type(4)));
typedef float f32x4 __attribute__((ext_vector_type(4)));

#define MFMA16(A, B, C) __builtin_amdgcn_mfma_f32_16x16x32_bf16(A, B, C, 0, 0, 0)

// MFMA 16x16x32 bf16 fragment conventions:
//   A-frag: lane = quad*16+l16 holds A[m=l16][k=quad*8+j]
//   B-frag: lane = quad*16+l16 holds B[k=quad*8+j][n=l16]
//   C/D   : lane holds D[m=quad*4+reg][n=l16]
// Frag-ordered buffers store one 32k x 16n B-tile as [lane][8] -> one
// coalesced 16B/lane read.  K/V frag base for (b,kt) = ((b*32+kt)*8)*512.

// ---------------------------------------------------------------------------
__global__ __launch_bounds__(256) void wt_convert(
    const float* __restrict__ Wq, const float* __restrict__ Wk,
    const float* __restrict__ Wv, bf16_t* __restrict__ Wtf)
{
    int id = blockIdx.x * 256 + threadIdx.x;      // 0 .. 196607
    int j = id & 7;
    int lane = (id >> 3) & 63;
    int chunk = (id >> 9) & 31;
    int nt = id >> 14;
    int l16 = lane & 15, quad = lane >> 4;
    int k = chunk * 32 + quad * 8 + j;
    int col = nt * 16 + l16;
    int m = col >> 6, ncol = col & 63;
    const float* W = (m == 0) ? Wq : (m == 1) ? Wk : Wv;
    float scl = (m == 0) ? 0.18033688f : 1.0f;    // 0.125 * log2(e)
    Wtf[id] = (bf16_t)(W[k * HSZ + ncol] * scl);
}

// ---------------------------------------------------------------------------
// QKV projection, in-block k-split.  1024 blocks x 4 waves; wave w covers
// k in [w*256, w*256+256) for the block's 16 rows.
// r10 change: ctx staged through LDS with COALESCED loads (the old direct
// A-frag read had a 4KB lane stride -> 32 partially-used transactions of
// cold HBM per load, sitting in the serial k-chain).  Staging: thread tid,
// iter i -> row i, float4 col tid (consecutive lanes = consecutive 16B).
// A-frag in the k-loop is now one ds_read_b128 (row stride 1032 el = 129
// 16B-granules, odd -> full LDS BW).  Epilogue red[] unions into the
// staging buffer (33 KB total -> >=4 blocks/CU).
// ---------------------------------------------------------------------------
__global__ __launch_bounds__(256, 3) void qkv_proj(
    const float* __restrict__ ctx, const bf16_t* __restrict__ Wtf,
    bf16_t* __restrict__ Q, bf16_t* __restrict__ Kf, bf16_t* __restrict__ Vf)
{
    __shared__ __align__(16) char smem_raw[16 * 1032 * 2];   // 33 KB
    bf16_t (*As)[1032] = (bf16_t (*)[1032])smem_raw;         // staging view
    f32x4 (*red)[4][64] = (f32x4 (*)[4][64])smem_raw;        // epilogue view (16 KB)

    const int tid = threadIdx.x;
    const int w = tid >> 6, lane = tid & 63;
    const int quad = lane >> 4, l16 = lane & 15;
    const size_t row0 = (size_t)blockIdx.x * 16;
    const int k0 = w * 256;

    // ---- stage 16 ctx rows -> bf16 LDS, fully coalesced ----
    {
        const float4* csrc = (const float4*)(ctx + row0 * DD);
        #pragma unroll
        for (int i = 0; i < 16; ++i) {
            float4 v = csrc[i * 256 + tid];       // row i, col4 = tid
            bf16x4 bv;
            bv[0] = (bf16_t)v.x; bv[1] = (bf16_t)v.y;
            bv[2] = (bf16_t)v.z; bv[3] = (bf16_t)v.w;
            *(bf16x4*)&As[i][tid * 4] = bv;
        }
    }
    __syncthreads();

    f32x4 acc[12];
    #pragma unroll
    for (int i = 0; i < 12; ++i) acc[i] = (f32x4){0.f, 0.f, 0.f, 0.f};

    const bf16_t* wbase = Wtf + lane * 8;

    #pragma unroll
    for (int kc = 0; kc < 256; kc += 32) {
        const int chunk = (k0 + kc) >> 5;
        bf16x8 bfr[12];
        #pragma unroll
        for (int nt = 0; nt < 12; ++nt)
            bfr[nt] = *(const bf16x8*)(wbase + ((size_t)nt * 32 + chunk) * 512);
        bf16x8 af = *(const bf16x8*)&As[l16][k0 + kc + quad * 8];   // ds_read_b128
        #pragma unroll
        for (int nt = 0; nt < 12; ++nt)
            acc[nt] = MFMA16(af, bfr[nt], acc[nt]);
    }
    __syncthreads();   // all As reads done before red reuse

    const int bb   = (int)(row0 >> 11);
    const int tloc = (int)(row0 & 2047);
    const int kt   = tloc >> 6;
    const int nn   = (tloc >> 4) & 3;

    #pragma unroll
    for (int r = 0; r < 3; ++r) {
        if (r) __syncthreads();                 // buffer reuse between rounds
        #pragma unroll
        for (int i = 0; i < 4; ++i) red[w][i][lane] = acc[r * 4 + i];
        __syncthreads();

        f32x4 s = red[0][w][lane];
        s += red[1][w][lane];
        s += red[2][w][lane];
        s += red[3][w][lane];

        if (r == 0) {          // Q col-tile w, row-major
            const int col = w * 16 + l16;
            #pragma unroll
            for (int reg = 0; reg < 4; ++reg)
                Q[(row0 + quad * 4 + reg) * HSZ + col] = (bf16_t)s[reg];
        } else if (r == 1) {   // K -> frag order (kt, n=nn, ks); g = w
            const int ks = w >> 1;
            const int quadf = (w & 1) * 2 + (l16 >> 3);
            const int jj = l16 & 7;
            const size_t fb = ((((size_t)bb * 32 + kt) * 4 + nn) * 2 + ks) * 512;
            #pragma unroll
            for (int reg = 0; reg < 4; ++reg)
                Kf[fb + (quadf * 16 + quad * 4 + reg) * 8 + jj] = (bf16_t)s[reg];
        } else {               // V -> frag order (kt, ks, dt=w)
            const int t0 = tloc + quad * 4;
            const int ks = (t0 >> 5) & 1;
            const int quadf = (t0 >> 3) & 3;
            const int j0 = t0 & 7;
            const size_t fb = ((((size_t)bb * 32 + kt) * 2 + ks) * 4 + w) * 512;
            bf16x4 v;
            #pragma unroll
            for (int reg = 0; reg < 4; ++reg) v[reg] = (bf16_t)s[reg];
            *(bf16x4*)(Vf + fb + (quadf * 16 + l16) * 8 + j0) = v;
        }
    }
}

// ---------------------------------------------------------------------------
// Split-K=4 flash attention; K frags double-buffered across k-tiles.
// (unchanged from r9)
// ---------------------------------------------------------------------------
__device__ __forceinline__ void load_kfrags(
    const bf16_t* __restrict__ Kf, size_t bofs, int kt, int lane, bf16x8* kf)
{
    const bf16_t* kbase = Kf + ((bofs + (size_t)kt) * 8) * 512 + lane * 8;
    #pragma unroll
    for (int i = 0; i < 8; ++i)
        kf[i] = *(const bf16x8*)(kbase + i * 512);
}

__global__ __launch_bounds__(64, 3) void attn_kernel(
    const bf16_t* __restrict__ Q, const bf16_t* __restrict__ Kf,
    const bf16_t* __restrict__ Vf,
    float* __restrict__ Opart, float* __restrict__ Lpart)
{
    __shared__ bf16_t Ps[16][76];

    const int lane = threadIdx.x;
    const int quad = lane >> 4, l16 = lane & 15;

    const int z = blockIdx.x;
    const int b = z & 7, c = z >> 3;
    const int j = 127 - (c >> 2);
    const int seg = c & 3;
    const size_t base = (size_t)b * TT * HSZ;
    const size_t bofs = (size_t)b * 32;           // tile units
    const int ntile = (j >> 2) + 1, jm = j & 3;

    const bf16_t* qp = Q + base + (size_t)(j * 16 + l16) * HSZ + quad * 8;
    bf16x8 qf0 = *(const bf16x8*)qp;
    bf16x8 qf1 = *(const bf16x8*)(qp + 32);

    bf16x8 onesf;
    {
        bf16_t e = (l16 == 0) ? (bf16_t)1.0f : (bf16_t)0.0f;
        #pragma unroll
        for (int i = 0; i < 8; ++i) onesf[i] = e;
    }

    f32x4 o[4];
    #pragma unroll
    for (int dt = 0; dt < 4; ++dt) o[dt] = (f32x4){0.f, 0.f, 0.f, 0.f};
    f32x4 lacc = (f32x4){0.f, 0.f, 0.f, 0.f};

    bf16x8 kA[8], kB[8];

    auto process = [&](int kt, const bf16x8* kf) {
        const bool last = (kt == ntile - 1);
        const int nv = last ? jm + 1 : 4;
        const int ksm = (nv > 2) ? 2 : 1;

        const bf16_t* vbase = Vf + ((bofs + (size_t)kt) * 8) * 512 + lane * 8;
        bf16x8 vf[8];
        #pragma unroll
        for (int i = 0; i < 8; ++i)
            vf[i] = *(const bf16x8*)(vbase + i * 512);   // [dt] then [4+dt]

        f32x4 sc[4];
        #pragma unroll
        for (int n = 0; n < 4; ++n) {
            if (n < nv) {
                f32x4 a = (f32x4){0.f, 0.f, 0.f, 0.f};
                a = MFMA16(qf0, kf[2 * n], a);
                a = MFMA16(qf1, kf[2 * n + 1], a);
                sc[n] = a;
            }
        }

        if (last) {
            #pragma unroll
            for (int n = 0; n < 4; ++n) {
                if (n < nv) {
                    #pragma unroll
                    for (int reg = 0; reg < 4; ++reg) {
                        bool masked = (n == jm) && (l16 > quad * 4 + reg);
                        float p = __builtin_amdgcn_exp2f(sc[n][reg]);
                        sc[n][reg] = masked ? 0.f : p;
                    }
                }
            }
        } else {
            #pragma unroll
            for (int n = 0; n < 4; ++n)
                #pragma unroll
                for (int reg = 0; reg < 4; ++reg)
                    sc[n][reg] = __builtin_amdgcn_exp2f(sc[n][reg]);
        }

        #pragma unroll
        for (int n = 0; n < 4; ++n) {
            #pragma unroll
            for (int reg = 0; reg < 4; ++reg) {
                float p = (n < nv) ? sc[n][reg] : 0.f;
                Ps[quad * 4 + reg][n * 16 + l16] = (bf16_t)p;
            }
        }
        bf16x8 pf0 = *(const bf16x8*)&Ps[l16][quad * 8];
        bf16x8 pf1 = *(const bf16x8*)&Ps[l16][32 + quad * 8];

        #pragma unroll
        for (int dt = 0; dt < 4; ++dt) {
            o[dt] = MFMA16(pf0, vf[dt], o[dt]);
            if (ksm == 2) o[dt] = MFMA16(pf1, vf[4 + dt], o[dt]);
        }
        lacc = MFMA16(pf0, onesf, lacc);
        if (ksm == 2) lacc = MFMA16(pf1, onesf, lacc);
    };

    // software-pipelined pair loop: load(t+4) before process(t)
    if (seg < ntile) {
        load_kfrags(Kf, bofs, seg, lane, kA);
        for (int kt = seg; kt < ntile; kt += 8) {
            if (kt + 4 < ntile) load_kfrags(Kf, bofs, kt + 4, lane, kB);
            process(kt, kA);
            if (kt + 4 < ntile) {
                if (kt + 8 < ntile) load_kfrags(Kf, bofs, kt + 8, lane, kA);
                process(kt + 4, kB);
            }
        }
    }

    float* op = Opart + (size_t)z * 16 * 64;
    #pragma unroll
    for (int dt = 0; dt < 4; ++dt) {
        #pragma unroll
        for (int reg = 0; reg < 4; ++reg)
            op[(quad * 4 + reg) * 64 + dt * 16 + l16] = o[dt][reg];
    }
    if (l16 == 0) {
        #pragma unroll
        for (int reg = 0; reg < 4; ++reg)
            Lpart[z * 16 + quad * 4 + reg] = lacc[reg];
    }
}

// ---------------------------------------------------------------------------
__global__ __launch_bounds__(256) void combine_kernel(
    const float* __restrict__ Opart, const float* __restrict__ Lpart,
    float* __restrict__ O)
{
    int gid = blockIdx.x * 256 + threadIdx.x;   // 0 .. 1048575
    int col = gid & 63;
    int row = (gid >> 6) & 15;
    int j   = (gid >> 10) & 127;
    int b   = gid >> 17;
    int z0 = ((127 - j) * 4) * 8 + b;
    float l = 0.f, ov = 0.f;
    #pragma unroll
    for (int s = 0; s < 4; ++s) {
        l  += Lpart[(z0 + 8 * s) * 16 + row];
        ov += Opart[((size_t)(z0 + 8 * s) * 16 + row) * 64 + col];
    }
    O[((size_t)b * TT + j * 16 + row) * 64 + col] = ov / l;
}

// ---------------------------------------------------------------------------
extern "C" void kernel_launch(void* const* d_in, const int* in_sizes, int n_in,
                              void* d_out, int out_size, void* d_ws, size_t ws_size,
                              hipStream_t stream) {
    const float* ctx = (const float*)d_in[0];
    const float* Wq  = (const float*)d_in[1];
    const float* Wk  = (const float*)d_in[2];
    const float* Wv  = (const float*)d_in[3];
    float* out = (float*)d_out;

    const size_t NQ = (size_t)BB * TT * HSZ;       // 1,048,576
    bf16_t* Qw  = (bf16_t*)d_ws;
    bf16_t* Kfw = Qw + NQ;                         // frag-ordered
    bf16_t* Vfw = Kfw + NQ;                        // frag-ordered
    bf16_t* Wtf = Vfw + NQ;                        // frag-ordered
    float*  Opart = (float*)(Wtf + 196608);        // [4096][16][64]
    float*  Lpart = Opart + (size_t)4096 * 1024;   // [4096][16]

    wt_convert<<<768, 256, 0, stream>>>(Wq, Wk, Wv, Wtf);
    qkv_proj<<<1024, 256, 0, stream>>>(ctx, Wtf, Qw, Kfw, Vfw);
    attn_kernel<<<4096, 64, 0, stream>>>(Qw, Kfw, Vfw, Opart, Lpart);
    combine_kernel<<<4096, 256, 0, stream>>>(Opart, Lpart, out);
}

// Round 11
// 122.752 us; speedup vs baseline: 1.1706x; 1.0470x over previous
//
#include <hip/hip_runtime.h>
#include <math.h>

#define BB 8
#define TT 2048
#define DD 1024
#define HSZ 64

typedef __bf16 bf16_t;
typedef bf16_t bf16x8 __attribute__((ext_vector_type(8)));
typedef bf16_t bf16x4 __attribute__((ext_vector_type(4)));
typedef float f32x4 __attribute__((ext_vector_type(4)));

#define MFMA16(A, B, C) __builtin_amdgcn_mfma_f32_16x16x32_bf16(A, B, C, 0, 0, 0)

// MFMA 16x16x32 bf16 fragment conventions:
//   A-frag: lane = quad*16+l16 holds A[m=l16][k=quad*8+j]
//   B-frag: lane = quad*16+l16 holds B[k=quad*8+j][n=l16]
//   C/D   : lane holds D[m=quad*4+reg][n=l16]
// A-frag and B-frag lane layouts are IDENTICAL w.r.t. their own matrix
// (lane holds 8 k-elements of one row/col), so Kf/Vf/Q loads serve as
// either operand.  r11: compute S^T = K Q^T and O^T = Vt P^T -> P-store
// is 4x ds_write_b64, epilogue is f32x4, row-sum l via all-ones A-frag.
// K/V frag base for (b,kt) = ((b*32+kt)*8)*512.

// ---------------------------------------------------------------------------
__global__ __launch_bounds__(256) void wt_convert(
    const float* __restrict__ Wq, const float* __restrict__ Wk,
    const float* __restrict__ Wv, bf16_t* __restrict__ Wtf)
{
    int id = blockIdx.x * 256 + threadIdx.x;      // 0 .. 196607
    int j = id & 7;
    int lane = (id >> 3) & 63;
    int chunk = (id >> 9) & 31;
    int nt = id >> 14;
    int l16 = lane & 15, quad = lane >> 4;
    int k = chunk * 32 + quad * 8 + j;
    int col = nt * 16 + l16;
    int m = col >> 6, ncol = col & 63;
    const float* W = (m == 0) ? Wq : (m == 1) ? Wk : Wv;
    float scl = (m == 0) ? 0.18033688f : 1.0f;    // 0.125 * log2(e)
    Wtf[id] = (bf16_t)(W[k * HSZ + ncol] * scl);
}

// ---------------------------------------------------------------------------
// QKV projection (unchanged from r10): in-block k-split, LDS-staged ctx,
// frag-ordered outputs.
// ---------------------------------------------------------------------------
__global__ __launch_bounds__(256, 3) void qkv_proj(
    const float* __restrict__ ctx, const bf16_t* __restrict__ Wtf,
    bf16_t* __restrict__ Q, bf16_t* __restrict__ Kf, bf16_t* __restrict__ Vf)
{
    __shared__ __align__(16) char smem_raw[16 * 1032 * 2];   // 33 KB
    bf16_t (*As)[1032] = (bf16_t (*)[1032])smem_raw;
    f32x4 (*red)[4][64] = (f32x4 (*)[4][64])smem_raw;

    const int tid = threadIdx.x;
    const int w = tid >> 6, lane = tid & 63;
    const int quad = lane >> 4, l16 = lane & 15;
    const size_t row0 = (size_t)blockIdx.x * 16;
    const int k0 = w * 256;

    {
        const float4* csrc = (const float4*)(ctx + row0 * DD);
        #pragma unroll
        for (int i = 0; i < 16; ++i) {
            float4 v = csrc[i * 256 + tid];
            bf16x4 bv;
            bv[0] = (bf16_t)v.x; bv[1] = (bf16_t)v.y;
            bv[2] = (bf16_t)v.z; bv[3] = (bf16_t)v.w;
            *(bf16x4*)&As[i][tid * 4] = bv;
        }
    }
    __syncthreads();

    f32x4 acc[12];
    #pragma unroll
    for (int i = 0; i < 12; ++i) acc[i] = (f32x4){0.f, 0.f, 0.f, 0.f};

    const bf16_t* wbase = Wtf + lane * 8;

    #pragma unroll
    for (int kc = 0; kc < 256; kc += 32) {
        const int chunk = (k0 + kc) >> 5;
        bf16x8 bfr[12];
        #pragma unroll
        for (int nt = 0; nt < 12; ++nt)
            bfr[nt] = *(const bf16x8*)(wbase + ((size_t)nt * 32 + chunk) * 512);
        bf16x8 af = *(const bf16x8*)&As[l16][k0 + kc + quad * 8];
        #pragma unroll
        for (int nt = 0; nt < 12; ++nt)
            acc[nt] = MFMA16(af, bfr[nt], acc[nt]);
    }
    __syncthreads();

    const int bb   = (int)(row0 >> 11);
    const int tloc = (int)(row0 & 2047);
    const int kt   = tloc >> 6;
    const int nn   = (tloc >> 4) & 3;

    #pragma unroll
    for (int r = 0; r < 3; ++r) {
        if (r) __syncthreads();
        #pragma unroll
        for (int i = 0; i < 4; ++i) red[w][i][lane] = acc[r * 4 + i];
        __syncthreads();

        f32x4 s = red[0][w][lane];
        s += red[1][w][lane];
        s += red[2][w][lane];
        s += red[3][w][lane];

        if (r == 0) {          // Q col-tile w, row-major
            const int col = w * 16 + l16;
            #pragma unroll
            for (int reg = 0; reg < 4; ++reg)
                Q[(row0 + quad * 4 + reg) * HSZ + col] = (bf16_t)s[reg];
        } else if (r == 1) {   // K -> frag order (kt, n=nn, ks); g = w
            const int ks = w >> 1;
            const int quadf = (w & 1) * 2 + (l16 >> 3);
            const int jj = l16 & 7;
            const size_t fb = ((((size_t)bb * 32 + kt) * 4 + nn) * 2 + ks) * 512;
            #pragma unroll
            for (int reg = 0; reg < 4; ++reg)
                Kf[fb + (quadf * 16 + quad * 4 + reg) * 8 + jj] = (bf16_t)s[reg];
        } else {               // V -> frag order (kt, ks, dt=w)
            const int t0 = tloc + quad * 4;
            const int ks = (t0 >> 5) & 1;
            const int quadf = (t0 >> 3) & 3;
            const int j0 = t0 & 7;
            const size_t fb = ((((size_t)bb * 32 + kt) * 2 + ks) * 4 + w) * 512;
            bf16x4 v;
            #pragma unroll
            for (int reg = 0; reg < 4; ++reg) v[reg] = (bf16_t)s[reg];
            *(bf16x4*)(Vf + fb + (quadf * 16 + l16) * 8 + j0) = v;
        }
    }
}

// ---------------------------------------------------------------------------
// Fused flash attention: block = (b, q-strip j), 4 waves; wave w handles
// tiles kt = w, w+4, ... (split-K inside the block).  Transposed algebra:
//   S^T = K(A) Q^T(B)   -> lane holds 4 consecutive keys for one query
//   O^T = Vt(A) P^T(B)  -> lane holds 4 consecutive d for one query
//   l = ones(A) P^T(B)  -> every lane holds l[query=l16]
// Final cross-wave O/l reduction via LDS, divide, coalesced float4 store.
// No Opart/Lpart, no combine kernel.
// ---------------------------------------------------------------------------
__device__ __forceinline__ void load_kfrags(
    const bf16_t* __restrict__ Kf, size_t bofs, int kt, int lane, bf16x8* kf)
{
    const bf16_t* kbase = Kf + ((bofs + (size_t)kt) * 8) * 512 + lane * 8;
    #pragma unroll
    for (int i = 0; i < 8; ++i)
        kf[i] = *(const bf16x8*)(kbase + i * 512);
}

__global__ __launch_bounds__(256, 3) void attn_kernel(
    const bf16_t* __restrict__ Q, const bf16_t* __restrict__ Kf,
    const bf16_t* __restrict__ Vf, float* __restrict__ O)
{
    __shared__ bf16_t Ps[4][16][72];     // per-wave P, [query][key], 9 KB
    __shared__ float Ored[4][16][68];    // per-wave O^T partials, 17.4 KB
    __shared__ float Lred[4][16];

    const int tid = threadIdx.x;
    const int w = tid >> 6, lane = tid & 63;
    const int quad = lane >> 4, l16 = lane & 15;

    const int z = blockIdx.x;
    const int b = z & 7;
    const int j = 127 - (z >> 3);        // long strips dispatch first
    const size_t base = (size_t)b * TT * HSZ;
    const size_t bofs = (size_t)b * 32;  // tile units
    const int ntile = (j >> 2) + 1, jm = j & 3;

    // Q as B-operand (Q^T): same row-major load as before
    const bf16_t* qp = Q + base + (size_t)(j * 16 + l16) * HSZ + quad * 8;
    bf16x8 qf0 = *(const bf16x8*)qp;
    bf16x8 qf1 = *(const bf16x8*)(qp + 32);

    bf16x8 onesA;                        // all-ones A-frag for the row-sum
    #pragma unroll
    for (int i = 0; i < 8; ++i) onesA[i] = (bf16_t)1.0f;

    f32x4 o[4];
    #pragma unroll
    for (int dt = 0; dt < 4; ++dt) o[dt] = (f32x4){0.f, 0.f, 0.f, 0.f};
    f32x4 lacc = (f32x4){0.f, 0.f, 0.f, 0.f};

    bf16x8 kA[8], kB[8];

    auto process = [&](int kt, const bf16x8* kf) {
        const bool last = (kt == ntile - 1);
        const int nv = last ? jm + 1 : 4;
        const int ksm = (nv > 2) ? 2 : 1;

        const bf16_t* vbase = Vf + ((bofs + (size_t)kt) * 8) * 512 + lane * 8;
        bf16x8 vf[8];
        #pragma unroll
        for (int i = 0; i < 8; ++i)
            vf[i] = *(const bf16x8*)(vbase + i * 512);   // ks0: dt 0..3, ks1: 4..7

        // ---- S^T = K Q^T (subtile n: keys n*16..+15 x 16 queries) ----
        f32x4 sc[4];
        #pragma unroll
        for (int n = 0; n < 4; ++n) {
            if (n < nv) {
                f32x4 a = (f32x4){0.f, 0.f, 0.f, 0.f};
                a = MFMA16(kf[2 * n], qf0, a);
                a = MFMA16(kf[2 * n + 1], qf1, a);
                sc[n] = a;
            }
        }

        // ---- p = exp2(s); transposed causal mask: key > query ----
        if (last) {
            #pragma unroll
            for (int n = 0; n < 4; ++n) {
                if (n < nv) {
                    #pragma unroll
                    for (int reg = 0; reg < 4; ++reg) {
                        bool masked = (n == jm) && (quad * 4 + reg > l16);
                        float p = __builtin_amdgcn_exp2f(sc[n][reg]);
                        sc[n][reg] = masked ? 0.f : p;
                    }
                }
            }
        } else {
            #pragma unroll
            for (int n = 0; n < 4; ++n)
                #pragma unroll
                for (int reg = 0; reg < 4; ++reg)
                    sc[n][reg] = __builtin_amdgcn_exp2f(sc[n][reg]);
        }

        // ---- P -> LDS: lane writes 4 consecutive keys (one b64) per n ----
        #pragma unroll
        for (int n = 0; n < 4; ++n) {
            bf16x4 pv;
            #pragma unroll
            for (int reg = 0; reg < 4; ++reg)
                pv[reg] = (bf16_t)((n < nv) ? sc[n][reg] : 0.f);
            *(bf16x4*)&Ps[w][l16][n * 16 + quad * 4] = pv;
        }
        // P^T B-frags: lane reads Ps[w][query=l16][key=quad*8+jj]
        bf16x8 pf0 = *(const bf16x8*)&Ps[w][l16][quad * 8];
        bf16x8 pf1 = *(const bf16x8*)&Ps[w][l16][32 + quad * 8];

        // ---- O^T += Vt P^T ;  l += 1 P^T ----
        #pragma unroll
        for (int dt = 0; dt < 4; ++dt) {
            o[dt] = MFMA16(vf[dt], pf0, o[dt]);
            if (ksm == 2) o[dt] = MFMA16(vf[4 + dt], pf1, o[dt]);
        }
        lacc = MFMA16(onesA, pf0, lacc);
        if (ksm == 2) lacc = MFMA16(onesA, pf1, lacc);
    };

    // software-pipelined: wave w owns kt = w, w+4, ...; load(t+4) before
    // process(t).  Inactive waves (w >= ntile) still reach the barrier.
    if (w < ntile) {
        load_kfrags(Kf, bofs, w, lane, kA);
        for (int kt = w; kt < ntile; kt += 8) {
            if (kt + 4 < ntile) load_kfrags(Kf, bofs, kt + 4, lane, kB);
            process(kt, kA);
            if (kt + 4 < ntile) {
                if (kt + 8 < ntile) load_kfrags(Kf, bofs, kt + 8, lane, kA);
                process(kt + 4, kB);
            }
        }
    }

    // ---- cross-wave reduction: O = (sum O^T) / (sum l) ----
    #pragma unroll
    for (int dt = 0; dt < 4; ++dt)
        *(f32x4*)&Ored[w][l16][dt * 16 + quad * 4] = o[dt];
    if (quad == 0) Lred[w][l16] = lacc[0];
    __syncthreads();

    const int query = tid >> 4, d4 = tid & 15;
    float l = Lred[0][query] + Lred[1][query] + Lred[2][query] + Lred[3][query];
    f32x4 s = *(const f32x4*)&Ored[0][query][d4 * 4];
    s += *(const f32x4*)&Ored[1][query][d4 * 4];
    s += *(const f32x4*)&Ored[2][query][d4 * 4];
    s += *(const f32x4*)&Ored[3][query][d4 * 4];
    const float linv = 1.f / l;
    float4 outv = make_float4(s[0] * linv, s[1] * linv, s[2] * linv, s[3] * linv);
    *(float4*)(O + base + (size_t)(j * 16 + query) * HSZ + d4 * 4) = outv;
}

// ---------------------------------------------------------------------------
extern "C" void kernel_launch(void* const* d_in, const int* in_sizes, int n_in,
                              void* d_out, int out_size, void* d_ws, size_t ws_size,
                              hipStream_t stream) {
    const float* ctx = (const float*)d_in[0];
    const float* Wq  = (const float*)d_in[1];
    const float* Wk  = (const float*)d_in[2];
    const float* Wv  = (const float*)d_in[3];
    float* out = (float*)d_out;

    const size_t NQ = (size_t)BB * TT * HSZ;       // 1,048,576
    bf16_t* Qw  = (bf16_t*)d_ws;
    bf16_t* Kfw = Qw + NQ;                         // frag-ordered
    bf16_t* Vfw = Kfw + NQ;                        // frag-ordered
    bf16_t* Wtf = Vfw + NQ;                        // frag-ordered

    wt_convert<<<768, 256, 0, stream>>>(Wq, Wk, Wv, Wtf);
    qkv_proj<<<1024, 256, 0, stream>>>(ctx, Wtf, Qw, Kfw, Vfw);
    attn_kernel<<<1024, 256, 0, stream>>>(Qw, Kfw, Vfw, out);
}